// Round 15
// baseline (419.590 us; speedup 1.0000x reference)
//
#include <hip/hip_runtime.h>
#include <hip/hip_bf16.h>

// ---------------------------------------------------------------------------
// GIN multi-task forward on MI355X.
// R15: gather fused INTO the MLP kernel (one dispatch per GIN layer).
// Rationale: 5 consecutive MLP structures all ~50us with every pipe <15% —
// intra-kernel tweaks exhausted. Gather (load-latency) and MLP (MFMA+L2)
// are complementary; fusing lets blocks in different phases co-schedule on
// a CU (m114). Kills the 25.6MB bufA nt-write + 25.6MB re-read per layer.
// Gather acc stays fp32, split hi/lo into LDS A-fragments (numerics
// unchanged). Layer-1 output mirror goes to xb2 (xb still being read).
// ---------------------------------------------------------------------------

#define IN_DIM 128
#define NFINE 256        // fine dst buckets (32 per XCD)
#define BIN_EPB 4096     // edges per bin block (16/thread)
#define SRCCH 16         // src chunks per dst row (sorted order)
#define NSLOT 3200       // >= ceil(n_nodes/NFINE) * SRCCH
#define SPT 7            // scan slots per thread (512*7 >= 3200)
#define HSTRIDE 136      // ushort; 272B rows keep every row 16B-aligned

typedef float  f32x4  __attribute__((ext_vector_type(4)));
typedef short  bf16x8 __attribute__((ext_vector_type(8)));

__device__ __forceinline__ unsigned short bf16_rne(float v) {
    unsigned u = __float_as_uint(v);
    unsigned t = u + 0x7fffu + ((u >> 16) & 1u);
    return (unsigned short)(t >> 16);
}

// ---------------- fp32 -> bf16 convert (RNE), 8 elems/thread ---------------

__global__ __launch_bounds__(256) void f32_to_bf16_kernel(
    const float4* __restrict__ in, uint4* __restrict__ out, int n8)
{
    int i = blockIdx.x * 256 + threadIdx.x;
    if (i >= n8) return;
    float4 a = in[i * 2];
    float4 b = in[i * 2 + 1];
    float v[8] = {a.x, a.y, a.z, a.w, b.x, b.y, b.z, b.w};
    unsigned r[4];
#pragma unroll
    for (int j = 0; j < 4; ++j)
        r[j] = (unsigned)bf16_rne(v[j * 2]) | ((unsigned)bf16_rne(v[j * 2 + 1]) << 16);
    out[i] = make_uint4(r[0], r[1], r[2], r[3]);
}

// ---------------- weight convert: W[k][n] fp32 -> Wt_h/Wt_l[n][k] bf16 -----

__global__ __launch_bounds__(256) void conv_weights_kernel(
    const float* __restrict__ W0, const float* __restrict__ W1,
    const float* __restrict__ W2, const float* __restrict__ W3,
    unsigned short* __restrict__ Wh, unsigned short* __restrict__ Wl)
{
    int m   = blockIdx.x >> 6;
    int idx = (blockIdx.x & 63) * 256 + threadIdx.x;
    const float* W = (m == 0) ? W0 : (m == 1) ? W1 : (m == 2) ? W2 : W3;
    int k = idx >> 7, n = idx & 127;
    float v = W[idx];
    unsigned short hh = bf16_rne(v);
    float hf = __uint_as_float(((unsigned)hh) << 16);
    unsigned short ll = bf16_rne(v - hf);
    Wh[m * 16384 + n * 128 + k] = hh;
    Wl[m * 16384 + n * 128 + k] = ll;
}

// ---------------- CSR build: 256-way bin (packed) -> fused hist/scan/fill --

__device__ __forceinline__ int bucket_lo(int b, int n_nodes) {
    return (int)(((long long)b * n_nodes + NFINE - 1) / NFINE);
}

__global__ __launch_bounds__(256) void bin_kernel(
    const int* __restrict__ src, const int* __restrict__ dst,
    int* __restrict__ buckets, int* __restrict__ bcur,
    int n_edges, int n_nodes, int cap)
{
    __shared__ int cnt[NFINE];
    __shared__ int base[NFINE];
    cnt[threadIdx.x] = 0;
    __syncthreads();

    const int e0 = blockIdx.x * BIN_EPB + threadIdx.x * 16;
    int ne = n_edges - e0;
    if (ne < 0) ne = 0;
    if (ne > 16) ne = 16;

    int d[16], s[16], off[16];
    if (ne == 16) {
#pragma unroll
        for (int q = 0; q < 4; ++q) {
            int4 dv = *(const int4*)(dst + e0 + q * 4);
            int4 sv = *(const int4*)(src + e0 + q * 4);
            d[q * 4 + 0] = dv.x; d[q * 4 + 1] = dv.y;
            d[q * 4 + 2] = dv.z; d[q * 4 + 3] = dv.w;
            s[q * 4 + 0] = sv.x; s[q * 4 + 1] = sv.y;
            s[q * 4 + 2] = sv.z; s[q * 4 + 3] = sv.w;
        }
    } else {
#pragma unroll
        for (int j = 0; j < 16; ++j) {
            d[j] = (j < ne) ? dst[e0 + j] : 0;
            s[j] = (j < ne) ? src[e0 + j] : 0;
        }
    }
#pragma unroll
    for (int j = 0; j < 16; ++j)
        if (j < ne) {
            int b = (int)(((long long)d[j] * NFINE) / n_nodes);
            off[j] = atomicAdd(&cnt[b], 1);
        }
    __syncthreads();
    base[threadIdx.x] = atomicAdd(&bcur[threadIdx.x], cnt[threadIdx.x]);
    __syncthreads();
#pragma unroll
    for (int j = 0; j < 16; ++j)
        if (j < ne) {
            int b = (int)(((long long)d[j] * NFINE) / n_nodes);
            int pack = ((d[j] - bucket_lo(b, n_nodes)) << 16) | s[j];
            buckets[(size_t)b * cap + base[b] + off[j]] = pack;
        }
}

__global__ __launch_bounds__(512) void csr_fused_kernel(
    const int* __restrict__ buckets, const int* __restrict__ bcnt,
    int* __restrict__ row_start, int* __restrict__ csr_src,
    int cap, int n_nodes, int n_edges)
{
    __shared__ int bc[NFINE];
    __shared__ int h[NSLOT];
    __shared__ int tsum[512];
    __shared__ int bbase_s;

    const int b = blockIdx.x;
    const int t = threadIdx.x;
    const int lo_n = bucket_lo(b, n_nodes);
    const int hi_n = bucket_lo(b + 1, n_nodes);
    const int sl = hi_n - lo_n;

    if (t < NFINE) bc[t] = bcnt[t];
    for (int i = t; i < NSLOT; i += 512) h[i] = 0;
    __syncthreads();
    if (t == 0) {
        int s = 0;
        for (int i = 0; i < b; ++i) s += bc[i];
        bbase_s = s;
    }
    const int nb = bc[b];
    const int* bp = buckets + (size_t)b * cap;
    __syncthreads();

    for (int i = t; i < nb; i += 512) {
        int v = bp[i];
        int key = (v >> 16) * SRCCH + (int)(((long long)(v & 0xFFFF) * SRCCH) / n_nodes);
        atomicAdd(&h[key], 1);
    }
    __syncthreads();

    int base = 0;
#pragma unroll
    for (int j = 0; j < SPT; ++j) {
        int slot = t * SPT + j;
        if (slot < NSLOT) {
            int v = h[slot];
            h[slot] = base;
            base += v;
        }
    }
    tsum[t] = base;
    __syncthreads();
    for (int off = 1; off < 512; off <<= 1) {
        int tmp = (t >= off) ? tsum[t - off] : 0;
        __syncthreads();
        tsum[t] += tmp;
        __syncthreads();
    }
    int texcl = tsum[t] - base + bbase_s;
#pragma unroll
    for (int j = 0; j < SPT; ++j) {
        int slot = t * SPT + j;
        if (slot < NSLOT) h[slot] += texcl;
    }
    __syncthreads();
    for (int i = t; i < sl; i += 512) row_start[lo_n + i] = h[i * SRCCH];
    if (b == NFINE - 1 && t == 0) row_start[n_nodes] = n_edges;
    __syncthreads();

    for (int i = t; i < nb; i += 512) {
        int v = bp[i];
        int key = (v >> 16) * SRCCH + (int)(((long long)(v & 0xFFFF) * SRCCH) / n_nodes);
        csr_src[atomicAdd(&h[key], 1)] = v & 0xFFFF;
    }
}

// ---------------- fused GIN layer: gather + MLP in one kernel --------------
// Block = 256 thr (4 waves), 64 rows.
// Phase G: standalone-gather structure (16 lanes/node, 4 rows/group),
//   fp32 acc = self + sum(bf16 neighbors), split hi/lo -> LDS Ah/Al.
// Phase 1: wave quadrant (32 rows x 64 cols) MFMA vs Wa, A-frags from LDS.
// Epilogue 1: h -> same LDS (after barrier). Phase 2: MFMA vs Wb.
// Epilogue 2: C fp32 (+ optional bf16 mirror to a SEPARATE buffer).

__device__ __forceinline__ void add_row8(float acc[8], uint4 r) {
    union { unsigned u; float f; } c;
    c.u = r.x << 16;         acc[0] += c.f;
    c.u = r.x & 0xffff0000u; acc[1] += c.f;
    c.u = r.y << 16;         acc[2] += c.f;
    c.u = r.y & 0xffff0000u; acc[3] += c.f;
    c.u = r.z << 16;         acc[4] += c.f;
    c.u = r.z & 0xffff0000u; acc[5] += c.f;
    c.u = r.w << 16;         acc[6] += c.f;
    c.u = r.w & 0xffff0000u; acc[7] += c.f;
}

template <bool EMIT_BF16>
__global__ __launch_bounds__(256) void fused_gin_layer_kernel(
    const float* __restrict__ Aself,     // fp32 node features (self term)
    const uint4* __restrict__ xb,        // bf16 rows, 16 uint4/row (neighbors)
    const int* __restrict__ row_start, const int* __restrict__ csr_src,
    const unsigned short* __restrict__ Wa_h, const unsigned short* __restrict__ Wa_l,
    const float* __restrict__ ba,
    const unsigned short* __restrict__ Wb_h, const unsigned short* __restrict__ Wb_l,
    const float* __restrict__ bb,
    float* __restrict__ C, unsigned short* __restrict__ Cb, int M)
{
    __shared__ __align__(16) unsigned short Ah[64][HSTRIDE];
    __shared__ __align__(16) unsigned short Al[64][HSTRIDE];

    const int t = threadIdx.x;

    // ---- phase G: gather into LDS (split bf16) ----
    {
        const int gl = t & 15;           // lane within node group (8 elems)
        const int gn = t >> 4;           // node group 0..15
        for (int rl = gn; rl < 64; rl += 16) {
            const int node = blockIdx.x * 64 + rl;
            float acc[8] = {0.f, 0.f, 0.f, 0.f, 0.f, 0.f, 0.f, 0.f};
            if (node < M) {
                const f32x4* sp = (const f32x4*)(Aself + (size_t)node * IN_DIM + gl * 8);
                f32x4 a0 = sp[0];
                f32x4 a1 = sp[1];
                acc[0] = a0.x; acc[1] = a0.y; acc[2] = a0.z; acc[3] = a0.w;
                acc[4] = a1.x; acc[5] = a1.y; acc[6] = a1.z; acc[7] = a1.w;
                int lo = row_start[node];
                int hi = row_start[node + 1];
                int e = lo;
                for (; e + 3 < hi; e += 4) {
                    int s0 = csr_src[e];
                    int s1 = csr_src[e + 1];
                    int s2 = csr_src[e + 2];
                    int s3 = csr_src[e + 3];
                    uint4 r0 = xb[(size_t)s0 * 16 + gl];
                    uint4 r1 = xb[(size_t)s1 * 16 + gl];
                    uint4 r2 = xb[(size_t)s2 * 16 + gl];
                    uint4 r3 = xb[(size_t)s3 * 16 + gl];
                    add_row8(acc, r0);
                    add_row8(acc, r1);
                    add_row8(acc, r2);
                    add_row8(acc, r3);
                }
                for (; e < hi; ++e)
                    add_row8(acc, xb[(size_t)csr_src[e] * 16 + gl]);
            }
            unsigned short hh[8], ll[8];
#pragma unroll
            for (int j = 0; j < 8; ++j) {
                unsigned short h = bf16_rne(acc[j]);
                hh[j] = h;
                ll[j] = bf16_rne(acc[j] - __uint_as_float(((unsigned)h) << 16));
            }
            *(uint4*)&Ah[rl][gl * 8] = *(uint4*)hh;   // 272B rows: 16B-aligned
            *(uint4*)&Al[rl][gl * 8] = *(uint4*)ll;
        }
    }
    __syncthreads();

    // ---- MLP: wave quadrant mapping ----
    const int wave = t >> 6;
    const int lane = t & 63;
    const int l15  = lane & 15;
    const int quad = lane >> 4;
    const int rw   = (wave & 1) * 32;
    const int cw   = (wave >> 1) * 64;
    const int row0 = blockIdx.x * 64 + rw;

    bf16x8 ah[2][4], al[2][4];
    // hoist A fragments from LDS
#pragma unroll
    for (int ti = 0; ti < 2; ++ti) {
        const int hr = rw + ti * 16 + l15;
#pragma unroll
        for (int k0c = 0; k0c < 4; ++k0c) {
            const int hk = k0c * 32 + quad * 8;
            ah[ti][k0c] = *(const bf16x8*)&Ah[hr][hk];
            al[ti][k0c] = *(const bf16x8*)&Al[hr][hk];
        }
    }
    __syncthreads();   // all A reads done before epilogue-1 overwrites LDS

    f32x4 acc[2][4];
#pragma unroll
    for (int ti = 0; ti < 2; ++ti)
#pragma unroll
        for (int ct = 0; ct < 4; ++ct) acc[ti][ct] = {0.f, 0.f, 0.f, 0.f};

    // ---- stage 1: A @ Wa (ct-outer) ----
#pragma unroll
    for (int ct = 0; ct < 4; ++ct) {
        const unsigned short* wph = Wa_h + (size_t)(cw + ct * 16 + l15) * IN_DIM + quad * 8;
        const unsigned short* wpl = Wa_l + (size_t)(cw + ct * 16 + l15) * IN_DIM + quad * 8;
        bf16x8 wh[4], wl[4];
#pragma unroll
        for (int k0c = 0; k0c < 4; ++k0c) {
            wh[k0c] = *(const bf16x8*)(wph + k0c * 32);
            wl[k0c] = *(const bf16x8*)(wpl + k0c * 32);
        }
#pragma unroll
        for (int k0c = 0; k0c < 4; ++k0c) {
            acc[0][ct] = __builtin_amdgcn_mfma_f32_16x16x32_bf16(ah[0][k0c], wh[k0c], acc[0][ct], 0, 0, 0);
            acc[1][ct] = __builtin_amdgcn_mfma_f32_16x16x32_bf16(ah[1][k0c], wh[k0c], acc[1][ct], 0, 0, 0);
            acc[0][ct] = __builtin_amdgcn_mfma_f32_16x16x32_bf16(al[0][k0c], wh[k0c], acc[0][ct], 0, 0, 0);
            acc[1][ct] = __builtin_amdgcn_mfma_f32_16x16x32_bf16(al[1][k0c], wh[k0c], acc[1][ct], 0, 0, 0);
            acc[0][ct] = __builtin_amdgcn_mfma_f32_16x16x32_bf16(ah[0][k0c], wl[k0c], acc[0][ct], 0, 0, 0);
            acc[1][ct] = __builtin_amdgcn_mfma_f32_16x16x32_bf16(ah[1][k0c], wl[k0c], acc[1][ct], 0, 0, 0);
        }
    }

    // ---- epilogue 1: h = relu(acc + ba) -> LDS (reuse Ah/Al) ----
#pragma unroll
    for (int ti = 0; ti < 2; ++ti) {
#pragma unroll
        for (int ct = 0; ct < 4; ++ct) {
            int col = cw + ct * 16 + l15;
            float b = ba[col];
#pragma unroll
            for (int r = 0; r < 4; ++r) {
                int rl = rw + ti * 16 + quad * 4 + r;
                float v = fmaxf(acc[ti][ct][r] + b, 0.f);
                unsigned short hh = bf16_rne(v);
                Ah[rl][col] = hh;
                Al[rl][col] = bf16_rne(v - __uint_as_float(((unsigned)hh) << 16));
            }
            acc[ti][ct] = {0.f, 0.f, 0.f, 0.f};
        }
    }
    __syncthreads();

    // ---- hoist H fragments from LDS ----
#pragma unroll
    for (int ti = 0; ti < 2; ++ti) {
        const int hr = rw + ti * 16 + l15;
#pragma unroll
        for (int k0c = 0; k0c < 4; ++k0c) {
            const int hk = k0c * 32 + quad * 8;
            ah[ti][k0c] = *(const bf16x8*)&Ah[hr][hk];
            al[ti][k0c] = *(const bf16x8*)&Al[hr][hk];
        }
    }

    // ---- stage 2: h @ Wb (ct-outer) ----
#pragma unroll
    for (int ct = 0; ct < 4; ++ct) {
        const unsigned short* wph = Wb_h + (size_t)(cw + ct * 16 + l15) * IN_DIM + quad * 8;
        const unsigned short* wpl = Wb_l + (size_t)(cw + ct * 16 + l15) * IN_DIM + quad * 8;
        bf16x8 wh[4], wl[4];
#pragma unroll
        for (int k0c = 0; k0c < 4; ++k0c) {
            wh[k0c] = *(const bf16x8*)(wph + k0c * 32);
            wl[k0c] = *(const bf16x8*)(wpl + k0c * 32);
        }
#pragma unroll
        for (int k0c = 0; k0c < 4; ++k0c) {
            acc[0][ct] = __builtin_amdgcn_mfma_f32_16x16x32_bf16(ah[0][k0c], wh[k0c], acc[0][ct], 0, 0, 0);
            acc[1][ct] = __builtin_amdgcn_mfma_f32_16x16x32_bf16(ah[1][k0c], wh[k0c], acc[1][ct], 0, 0, 0);
            acc[0][ct] = __builtin_amdgcn_mfma_f32_16x16x32_bf16(al[0][k0c], wh[k0c], acc[0][ct], 0, 0, 0);
            acc[1][ct] = __builtin_amdgcn_mfma_f32_16x16x32_bf16(al[1][k0c], wh[k0c], acc[1][ct], 0, 0, 0);
            acc[0][ct] = __builtin_amdgcn_mfma_f32_16x16x32_bf16(ah[0][k0c], wl[k0c], acc[0][ct], 0, 0, 0);
            acc[1][ct] = __builtin_amdgcn_mfma_f32_16x16x32_bf16(ah[1][k0c], wl[k0c], acc[1][ct], 0, 0, 0);
        }
    }

    // ---- epilogue 2: out = relu(acc + bb) -> C (+ bf16 mirror to Cb) ----
#pragma unroll
    for (int ti = 0; ti < 2; ++ti) {
        const int rbase = row0 + ti * 16 + quad * 4;
#pragma unroll
        for (int ct = 0; ct < 4; ++ct) {
            int col = cw + ct * 16 + l15;
            float b = bb[col];
#pragma unroll
            for (int r = 0; r < 4; ++r) {
                int row = rbase + r;
                if (row < M) {
                    float o = fmaxf(acc[ti][ct][r] + b, 0.f);
                    C[(size_t)row * IN_DIM + col] = o;
                    if (EMIT_BF16)
                        Cb[(size_t)row * IN_DIM + col] = bf16_rne(o);
                }
            }
        }
    }
}

// ---------------- pool + heads ---------------------------------------------

__device__ __forceinline__ int lower_bound_i(const int* __restrict__ a, int n, int v) {
    int lo = 0, hi = n;
    while (lo < hi) {
        int mid = (lo + hi) >> 1;
        if (a[mid] < v) lo = mid + 1; else hi = mid;
    }
    return lo;
}

__global__ __launch_bounds__(128) void pool_kernel(
    const float* __restrict__ h, const int* __restrict__ batch,
    float* __restrict__ pooled, int n_nodes, int n_graphs)
{
    int g = blockIdx.x;
    int lo = lower_bound_i(batch, n_nodes, g);
    int hi = lower_bound_i(batch, n_nodes, g + 1);
    int j = threadIdx.x;
    float acc = 0.f;
    for (int i = lo; i < hi; ++i)
        acc += h[(size_t)i * IN_DIM + j];
    float cnt = (float)(hi - lo);
    pooled[(size_t)g * IN_DIM + j] = acc / fmaxf(cnt, 1.0f);
}

__global__ __launch_bounds__(64) void head_kernel(
    const float* __restrict__ pooled,
    const float* __restrict__ Ws,  const float* __restrict__ bs,
    const float* __restrict__ WlS, const float* __restrict__ blS,
    const float* __restrict__ WlP, const float* __restrict__ blP,
    const float* __restrict__ WnR, const float* __restrict__ bnR,
    float* __restrict__ out, int n_graphs)
{
    int g = blockIdx.x;
    int j = threadIdx.x;
    const float* p = pooled + (size_t)g * IN_DIM;
    float acc = bs[j];
#pragma unroll 8
    for (int k = 0; k < IN_DIM; ++k)
        acc = fmaf(p[k], Ws[k * 64 + j], acc);
    float gj = fmaxf(acc, 0.f);
    float s1 = gj * WlS[j];
    float s2 = gj * WlP[j];
    float s3 = gj * WnR[j];
#pragma unroll
    for (int off = 32; off > 0; off >>= 1) {
        s1 += __shfl_down(s1, off);
        s2 += __shfl_down(s2, off);
        s3 += __shfl_down(s3, off);
    }
    if (j == 0) {
        out[g]                = s1 + blS[0];
        out[n_graphs + g]     = s2 + blP[0];
        out[2 * n_graphs + g] = s3 + bnR[0];
    }
}

// ---------------- launch ---------------------------------------------------

extern "C" void kernel_launch(void* const* d_in, const int* in_sizes, int n_in,
                              void* d_out, int out_size, void* d_ws, size_t ws_size,
                              hipStream_t stream)
{
    const float* x   = (const float*)d_in[0];
    const int*   ei  = (const int*)d_in[1];
    const int*   bat = (const int*)d_in[2];
    const float* W1a = (const float*)d_in[3];
    const float* b1a = (const float*)d_in[4];
    const float* W1b = (const float*)d_in[5];
    const float* b1b = (const float*)d_in[6];
    const float* W2a = (const float*)d_in[7];
    const float* b2a = (const float*)d_in[8];
    const float* W2b = (const float*)d_in[9];
    const float* b2b = (const float*)d_in[10];
    const float* Ws  = (const float*)d_in[11];
    const float* bs  = (const float*)d_in[12];
    const float* WlS = (const float*)d_in[13];
    const float* blS = (const float*)d_in[14];
    const float* WlP = (const float*)d_in[15];
    const float* blP = (const float*)d_in[16];
    const float* WnR = (const float*)d_in[17];
    const float* bnR = (const float*)d_in[18];

    const int n_nodes  = in_sizes[0] / IN_DIM;
    const int n_edges  = in_sizes[1] / 2;
    const int n_graphs = out_size / 3;
    const int* src = ei;
    const int* dst = ei + n_edges;

    const size_t node_elems   = (size_t)n_nodes * IN_DIM;
    const size_t pooled_elems = (size_t)n_graphs * IN_DIM;

    float* xbf    = (float*)d_ws;               // 2 bf16 mirrors (xb, xb2)
    float* buf2   = xbf  + node_elems;
    float* bufA   = buf2 + node_elems;          // buckets alias (CSR build only)
    float* pooled = bufA + node_elems;
    int* row_start = (int*)(pooled + pooled_elems);   // n_nodes + 1
    int* bcur      = row_start + (n_nodes + 1);       // NFINE bucket cursors
    int* csr_src   = bcur + NFINE;                    // n_edges
    unsigned short* wt_h = (unsigned short*)(csr_src + n_edges);  // 4 * 16384
    unsigned short* wt_l = wt_h + 4 * 16384;

    unsigned short* xb  = (unsigned short*)xbf;            // bf16 mirror of x
    unsigned short* xb2 = xb + node_elems;                 // bf16 mirror of h1-out
    const int cap = n_edges / NFINE + 1024;
    int* buckets = (int*)bufA;

    const int layerblocks = (n_nodes + 63) / 64;
    const int binblocks = (n_edges + BIN_EPB - 1) / BIN_EPB;
    const int n8 = (int)(node_elems / 8);
    const int cvtblocks = (n8 + 255) / 256;

    // ---- weight conversion + CSR build ----
    conv_weights_kernel<<<256, 256, 0, stream>>>(W1a, W1b, W2a, W2b, wt_h, wt_l);
    hipMemsetAsync(bcur, 0, NFINE * sizeof(int), stream);
    bin_kernel<<<binblocks, 256, 0, stream>>>(src, dst, buckets, bcur,
                                              n_edges, n_nodes, cap);
    csr_fused_kernel<<<NFINE, 512, 0, stream>>>(buckets, bcur, row_start,
                                                csr_src, cap, n_nodes, n_edges);

    // ---- layer 1 (gather + MLP fused); mirror of output -> xb2 ----
    f32_to_bf16_kernel<<<cvtblocks, 256, 0, stream>>>((const float4*)x, (uint4*)xb, n8);
    fused_gin_layer_kernel<true><<<layerblocks, 256, 0, stream>>>(
        x, (const uint4*)xb, row_start, csr_src,
        wt_h, wt_l, b1a, wt_h + 16384, wt_l + 16384, b1b,
        buf2, xb2, n_nodes);

    // ---- layer 2 (gather + MLP fused) ----
    fused_gin_layer_kernel<false><<<layerblocks, 256, 0, stream>>>(
        buf2, (const uint4*)xb2, row_start, csr_src,
        wt_h + 2 * 16384, wt_l + 2 * 16384, b2a,
        wt_h + 3 * 16384, wt_l + 3 * 16384, b2b,
        buf2, nullptr, n_nodes);

    // ---- pool + heads ----
    pool_kernel<<<n_graphs, 128, 0, stream>>>(buf2, bat, pooled, n_nodes, n_graphs);
    head_kernel<<<n_graphs, 64, 0, stream>>>(pooled, Ws, bs, WlS, blS, WlP, blP,
                                             WnR, bnR, (float*)d_out, n_graphs);
}

// Round 16
// 371.695 us; speedup vs baseline: 1.1289x; 1.1289x over previous
//
#include <hip/hip_runtime.h>
#include <hip/hip_bf16.h>

// ---------------------------------------------------------------------------
// GIN multi-task forward on MI355X.
// R16: revert to R13 structure (best, 372.9us) — R15's gather+MLP fusion
// regressed (124us/layer: 4x less gather TLP + 400K LDS bank conflicts).
// Single change vs R13: gather output stored with NORMAL stores (nt hint
// removed) — writer-block i and MLP reader-block i land on the same XCD
// (round-robin), so bufA stays L2-resident for the MLP's A loads (R14
// showed FETCH 13MB < 25.6MB even with nt; plain store should cut further).
// ---------------------------------------------------------------------------

#define IN_DIM 128
#define NFINE 128        // fine dst buckets (16 per XCD)
#define BIN_EPB 4096     // edges per bin block (16/thread)
#define SRCCH 16         // src chunks per dst row (sorted order)
#define NSLOT 6400       // >= 391 * SRCCH
#define SPT 13           // scan slots per thread (512*13 >= 6400)

typedef float  f32x4  __attribute__((ext_vector_type(4)));
typedef short  bf16x4 __attribute__((ext_vector_type(4)));
typedef short  bf16x8 __attribute__((ext_vector_type(8)));

__device__ __forceinline__ unsigned short bf16_rne(float v) {
    unsigned u = __float_as_uint(v);
    unsigned t = u + 0x7fffu + ((u >> 16) & 1u);
    return (unsigned short)(t >> 16);
}

// ---------------- fp32 -> bf16 convert (RNE), 8 elems/thread ---------------

__global__ __launch_bounds__(256) void f32_to_bf16_kernel(
    const float4* __restrict__ in, uint4* __restrict__ out, int n8)
{
    int i = blockIdx.x * 256 + threadIdx.x;
    if (i >= n8) return;
    float4 a = in[i * 2];
    float4 b = in[i * 2 + 1];
    float v[8] = {a.x, a.y, a.z, a.w, b.x, b.y, b.z, b.w};
    unsigned r[4];
#pragma unroll
    for (int j = 0; j < 4; ++j)
        r[j] = (unsigned)bf16_rne(v[j * 2]) | ((unsigned)bf16_rne(v[j * 2 + 1]) << 16);
    out[i] = make_uint4(r[0], r[1], r[2], r[3]);
}

// ---------------- weight convert: W[k][n] fp32 -> Wt_h/Wt_l[n][k] bf16 -----

__global__ __launch_bounds__(256) void conv_weights_kernel(
    const float* __restrict__ W0, const float* __restrict__ W1,
    const float* __restrict__ W2, const float* __restrict__ W3,
    unsigned short* __restrict__ Wh, unsigned short* __restrict__ Wl)
{
    int m   = blockIdx.x >> 6;
    int idx = (blockIdx.x & 63) * 256 + threadIdx.x;
    const float* W = (m == 0) ? W0 : (m == 1) ? W1 : (m == 2) ? W2 : W3;
    int k = idx >> 7, n = idx & 127;
    float v = W[idx];
    unsigned short hh = bf16_rne(v);
    float hf = __uint_as_float(((unsigned)hh) << 16);
    unsigned short ll = bf16_rne(v - hf);
    Wh[m * 16384 + n * 128 + k] = hh;
    Wl[m * 16384 + n * 128 + k] = ll;
}

// ---------------- CSR build: 128-way bin -> fused hist/scan/fill -----------

__global__ __launch_bounds__(256) void bin_kernel(
    const int* __restrict__ src, const int* __restrict__ dst,
    int2* __restrict__ buckets, int* __restrict__ bcur,
    int n_edges, int n_nodes, int cap)
{
    __shared__ int cnt[NFINE];
    __shared__ int base[NFINE];
    for (int i = threadIdx.x; i < NFINE; i += 256) cnt[i] = 0;
    __syncthreads();

    const int e0 = blockIdx.x * BIN_EPB + threadIdx.x * 16;
    int ne = n_edges - e0;
    if (ne < 0) ne = 0;
    if (ne > 16) ne = 16;

    int d[16], s[16], off[16];
    if (ne == 16) {
#pragma unroll
        for (int q = 0; q < 4; ++q) {
            int4 dv = *(const int4*)(dst + e0 + q * 4);
            int4 sv = *(const int4*)(src + e0 + q * 4);
            d[q * 4 + 0] = dv.x; d[q * 4 + 1] = dv.y;
            d[q * 4 + 2] = dv.z; d[q * 4 + 3] = dv.w;
            s[q * 4 + 0] = sv.x; s[q * 4 + 1] = sv.y;
            s[q * 4 + 2] = sv.z; s[q * 4 + 3] = sv.w;
        }
    } else {
#pragma unroll
        for (int j = 0; j < 16; ++j) {
            d[j] = (j < ne) ? dst[e0 + j] : 0;
            s[j] = (j < ne) ? src[e0 + j] : 0;
        }
    }
#pragma unroll
    for (int j = 0; j < 16; ++j)
        if (j < ne) {
            int b = (int)(((long long)d[j] * NFINE) / n_nodes);
            off[j] = atomicAdd(&cnt[b], 1);
        }
    __syncthreads();
    for (int i = threadIdx.x; i < NFINE; i += 256)
        base[i] = atomicAdd(&bcur[i], cnt[i]);
    __syncthreads();
#pragma unroll
    for (int j = 0; j < 16; ++j)
        if (j < ne) {
            int b = (int)(((long long)d[j] * NFINE) / n_nodes);
            buckets[(size_t)b * cap + base[b] + off[j]] = make_int2(d[j], s[j]);
        }
}

// One block per fine bucket. Per-(node, src-chunk16) LDS histogram, blocked
// exclusive scan (13 slots/thread), row_start write, LDS-cursor fill ->
// csr rows stored sorted by src chunk (gather L2 locality).
__global__ __launch_bounds__(512) void csr_fused_kernel(
    const int2* __restrict__ buckets, const int* __restrict__ bcnt,
    int* __restrict__ row_start, int* __restrict__ csr_src,
    int cap, int n_nodes, int n_edges)
{
    __shared__ int bc[NFINE];
    __shared__ int h[NSLOT];
    __shared__ int tsum[512];
    __shared__ int bbase_s;

    const int b = blockIdx.x;
    const int t = threadIdx.x;
    const int lo_n = (int)(((long long)b * n_nodes + NFINE - 1) / NFINE);
    const int hi_n = (int)(((long long)(b + 1) * n_nodes + NFINE - 1) / NFINE);
    const int sl = hi_n - lo_n;

    if (t < NFINE) bc[t] = bcnt[t];
    for (int i = t; i < NSLOT; i += 512) h[i] = 0;
    __syncthreads();
    if (t == 0) {
        int s = 0;
        for (int i = 0; i < b; ++i) s += bc[i];
        bbase_s = s;
    }
    const int nb = bc[b];
    const int2* bp = buckets + (size_t)b * cap;
    __syncthreads();

    // pass 1: per-(node, src-chunk) histogram
    for (int i = t; i < nb; i += 512) {
        int2 e = bp[i];
        int key = (e.x - lo_n) * SRCCH + (int)(((long long)e.y * SRCCH) / n_nodes);
        atomicAdd(&h[key], 1);
    }
    __syncthreads();

    // blocked exclusive scan over NSLOT entries (SPT per thread)
    int base = 0;
#pragma unroll
    for (int j = 0; j < SPT; ++j) {
        int slot = t * SPT + j;
        if (slot < NSLOT) {
            int v = h[slot];
            h[slot] = base;
            base += v;
        }
    }
    tsum[t] = base;
    __syncthreads();
    for (int off = 1; off < 512; off <<= 1) {
        int tmp = (t >= off) ? tsum[t - off] : 0;
        __syncthreads();
        tsum[t] += tmp;
        __syncthreads();
    }
    int texcl = tsum[t] - base + bbase_s;
#pragma unroll
    for (int j = 0; j < SPT; ++j) {
        int slot = t * SPT + j;
        if (slot < NSLOT) h[slot] += texcl;
    }
    __syncthreads();
    for (int i = t; i < sl; i += 512) row_start[lo_n + i] = h[i * SRCCH];
    if (b == NFINE - 1 && t == 0) row_start[n_nodes] = n_edges;
    __syncthreads();

    // pass 2: fill with LDS cursors (exclusive csr window, full-line writes)
    for (int i = t; i < nb; i += 512) {
        int2 e = bp[i];
        int key = (e.x - lo_n) * SRCCH + (int)(((long long)e.y * SRCCH) / n_nodes);
        csr_src[atomicAdd(&h[key], 1)] = e.y;
    }
}

// ---------------- gather aggregation (bf16 neighbors, fp32 self/acc) -------

__device__ __forceinline__ void add_row8(float acc[8], uint4 r) {
    union { unsigned u; float f; } c;
    c.u = r.x << 16;         acc[0] += c.f;
    c.u = r.x & 0xffff0000u; acc[1] += c.f;
    c.u = r.y << 16;         acc[2] += c.f;
    c.u = r.y & 0xffff0000u; acc[3] += c.f;
    c.u = r.z << 16;         acc[4] += c.f;
    c.u = r.z & 0xffff0000u; acc[5] += c.f;
    c.u = r.w << 16;         acc[6] += c.f;
    c.u = r.w & 0xffff0000u; acc[7] += c.f;
}

__global__ __launch_bounds__(256) void gather_agg_bf16_kernel(
    const float* __restrict__ xf,    // fp32 rows (self term)
    const uint4* __restrict__ xb,    // bf16 rows, 16 uint4/row
    const int* __restrict__ row_start, const int* __restrict__ csr_src,
    float* __restrict__ out, int n_nodes)
{
    int t = blockIdx.x * 256 + threadIdx.x;
    int node = t >> 4;
    int lane = t & 15;
    if (node >= n_nodes) return;
    int lo = row_start[node];
    int hi = row_start[node + 1];

    const f32x4* xfr = (const f32x4*)(xf + (size_t)node * IN_DIM + lane * 8);
    f32x4 a0 = __builtin_nontemporal_load(xfr);
    f32x4 a1 = __builtin_nontemporal_load(xfr + 1);
    float acc[8] = {a0.x, a0.y, a0.z, a0.w, a1.x, a1.y, a1.z, a1.w};

    int e = lo;
    for (; e + 3 < hi; e += 4) {
        int s0 = csr_src[e];
        int s1 = csr_src[e + 1];
        int s2 = csr_src[e + 2];
        int s3 = csr_src[e + 3];
        uint4 r0 = xb[(size_t)s0 * 16 + lane];
        uint4 r1 = xb[(size_t)s1 * 16 + lane];
        uint4 r2 = xb[(size_t)s2 * 16 + lane];
        uint4 r3 = xb[(size_t)s3 * 16 + lane];
        add_row8(acc, r0);
        add_row8(acc, r1);
        add_row8(acc, r2);
        add_row8(acc, r3);
    }
    for (; e < hi; ++e) {
        uint4 r = xb[(size_t)csr_src[e] * 16 + lane];
        add_row8(acc, r);
    }

    // NORMAL stores (R16 change): keep bufA L2-resident for the MLP reader
    // on the same XCD (round-robin block dispatch aligns writer/reader).
    f32x4* op = (f32x4*)(out + (size_t)node * IN_DIM + lane * 8);
    op[0] = (f32x4){acc[0], acc[1], acc[2], acc[3]};
    op[1] = (f32x4){acc[4], acc[5], acc[6], acc[7]};
}

// ---------------- fused MLP: relu(relu(A@Wa+ba)@Wb+bb) ---------------------
// Block = 256 thr (4 waves), 64 rows x 128 cols. Each wave owns a 32-row x
// 64-col quadrant: 2 row-tiles x 4 col-tiles = 8 indep acc chains, W shared
// across row-tiles (6 MFMAs per 2 W loads). (R13 structure.)
#define HSTRIDE 132

template <bool EMIT_BF16>
__global__ __launch_bounds__(256) void fused_mlp_kernel(
    const float* __restrict__ A,
    const unsigned short* __restrict__ Wa_h, const unsigned short* __restrict__ Wa_l,
    const float* __restrict__ ba,
    const unsigned short* __restrict__ Wb_h, const unsigned short* __restrict__ Wb_l,
    const float* __restrict__ bb,
    float* __restrict__ C, unsigned short* __restrict__ Cb, int M)
{
    __shared__ __align__(16) unsigned short Hh[64][HSTRIDE];
    __shared__ __align__(16) unsigned short Hl[64][HSTRIDE];

    const int t    = threadIdx.x;
    const int wave = t >> 6;
    const int lane = t & 63;
    const int l15  = lane & 15;
    const int quad = lane >> 4;
    const int rw   = (wave & 1) * 32;        // row quadrant base within block
    const int cw   = (wave >> 1) * 64;       // col quadrant base
    const int row0 = blockIdx.x * 64 + rw;

    f32x4 acc[2][4];
#pragma unroll
    for (int ti = 0; ti < 2; ++ti)
#pragma unroll
        for (int ct = 0; ct < 4; ++ct) acc[ti][ct] = {0.f, 0.f, 0.f, 0.f};

    // ---- stage 1: A (global fp32, split bf16) @ Wa ----
    {
        int ar0 = row0 + l15;
        int ar1 = row0 + 16 + l15;
        const float* ap0 = A + (size_t)((ar0 < M) ? ar0 : (M - 1)) * IN_DIM + quad * 8;
        const float* ap1 = A + (size_t)((ar1 < M) ? ar1 : (M - 1)) * IN_DIM + quad * 8;
#pragma unroll
        for (int k0 = 0; k0 < IN_DIM; k0 += 32) {
            bf16x8 ah[2], al[2];
#pragma unroll
            for (int ti = 0; ti < 2; ++ti) {
                const float* ap = ti ? ap1 : ap0;
                f32x4 v0 = *(const f32x4*)(ap + k0);
                f32x4 v1 = *(const f32x4*)(ap + k0 + 4);
                float v[8] = {v0.x, v0.y, v0.z, v0.w, v1.x, v1.y, v1.z, v1.w};
                unsigned short h[8], l[8];
#pragma unroll
                for (int j = 0; j < 8; ++j) {
                    unsigned short hh = bf16_rne(v[j]);
                    h[j] = hh;
                    l[j] = bf16_rne(v[j] - __uint_as_float(((unsigned)hh) << 16));
                }
                ah[ti] = *(const bf16x8*)h;
                al[ti] = *(const bf16x8*)l;
            }
#pragma unroll
            for (int ct = 0; ct < 4; ++ct) {
                const size_t woff = (size_t)(cw + ct * 16 + l15) * IN_DIM + k0 + quad * 8;
                bf16x8 wh = *(const bf16x8*)(Wa_h + woff);
                bf16x8 wl = *(const bf16x8*)(Wa_l + woff);
                acc[0][ct] = __builtin_amdgcn_mfma_f32_16x16x32_bf16(ah[0], wh, acc[0][ct], 0, 0, 0);
                acc[1][ct] = __builtin_amdgcn_mfma_f32_16x16x32_bf16(ah[1], wh, acc[1][ct], 0, 0, 0);
                acc[0][ct] = __builtin_amdgcn_mfma_f32_16x16x32_bf16(al[0], wh, acc[0][ct], 0, 0, 0);
                acc[1][ct] = __builtin_amdgcn_mfma_f32_16x16x32_bf16(al[1], wh, acc[1][ct], 0, 0, 0);
                acc[0][ct] = __builtin_amdgcn_mfma_f32_16x16x32_bf16(ah[0], wl, acc[0][ct], 0, 0, 0);
                acc[1][ct] = __builtin_amdgcn_mfma_f32_16x16x32_bf16(ah[1], wl, acc[1][ct], 0, 0, 0);
            }
        }
    }

    // ---- epilogue 1: h = relu(acc + ba) -> LDS quadrant (split bf16) ----
#pragma unroll
    for (int ti = 0; ti < 2; ++ti) {
#pragma unroll
        for (int ct = 0; ct < 4; ++ct) {
            int col = cw + ct * 16 + l15;
            float b = ba[col];
#pragma unroll
            for (int r = 0; r < 4; ++r) {
                int rl = rw + ti * 16 + quad * 4 + r;
                float v = fmaxf(acc[ti][ct][r] + b, 0.f);
                unsigned short hh = bf16_rne(v);
                Hh[rl][col] = hh;
                Hl[rl][col] = bf16_rne(v - __uint_as_float(((unsigned)hh) << 16));
            }
            acc[ti][ct] = {0.f, 0.f, 0.f, 0.f};
        }
    }
    __syncthreads();

    // ---- stage 2: h (LDS, split bf16) @ Wb ----
#pragma unroll
    for (int k0 = 0; k0 < IN_DIM; k0 += 32) {
        const int hk = k0 + quad * 8;
        bf16x8 ah[2], al[2];
#pragma unroll
        for (int ti = 0; ti < 2; ++ti) {
            const int hr = rw + ti * 16 + l15;
            bf16x4 h0 = *(const bf16x4*)&Hh[hr][hk];
            bf16x4 h1 = *(const bf16x4*)&Hh[hr][hk + 4];
            bf16x4 l0 = *(const bf16x4*)&Hl[hr][hk];
            bf16x4 l1 = *(const bf16x4*)&Hl[hr][hk + 4];
            ah[ti] = __builtin_shufflevector(h0, h1, 0, 1, 2, 3, 4, 5, 6, 7);
            al[ti] = __builtin_shufflevector(l0, l1, 0, 1, 2, 3, 4, 5, 6, 7);
        }
#pragma unroll
        for (int ct = 0; ct < 4; ++ct) {
            const size_t woff = (size_t)(cw + ct * 16 + l15) * IN_DIM + k0 + quad * 8;
            bf16x8 wh = *(const bf16x8*)(Wb_h + woff);
            bf16x8 wl = *(const bf16x8*)(Wb_l + woff);
            acc[0][ct] = __builtin_amdgcn_mfma_f32_16x16x32_bf16(ah[0], wh, acc[0][ct], 0, 0, 0);
            acc[1][ct] = __builtin_amdgcn_mfma_f32_16x16x32_bf16(ah[1], wh, acc[1][ct], 0, 0, 0);
            acc[0][ct] = __builtin_amdgcn_mfma_f32_16x16x32_bf16(al[0], wh, acc[0][ct], 0, 0, 0);
            acc[1][ct] = __builtin_amdgcn_mfma_f32_16x16x32_bf16(al[1], wh, acc[1][ct], 0, 0, 0);
            acc[0][ct] = __builtin_amdgcn_mfma_f32_16x16x32_bf16(ah[0], wl, acc[0][ct], 0, 0, 0);
            acc[1][ct] = __builtin_amdgcn_mfma_f32_16x16x32_bf16(ah[1], wl, acc[1][ct], 0, 0, 0);
        }
    }

    // ---- epilogue 2: out = relu(acc + bb) -> C (+ bf16 mirror) ----
#pragma unroll
    for (int ti = 0; ti < 2; ++ti) {
        const int rbase = row0 + ti * 16 + quad * 4;
#pragma unroll
        for (int ct = 0; ct < 4; ++ct) {
            int col = cw + ct * 16 + l15;
            float b = bb[col];
#pragma unroll
            for (int r = 0; r < 4; ++r) {
                int row = rbase + r;
                if (row < M) {
                    float o = fmaxf(acc[ti][ct][r] + b, 0.f);
                    C[(size_t)row * IN_DIM + col] = o;
                    if (EMIT_BF16)
                        Cb[(size_t)row * IN_DIM + col] = bf16_rne(o);
                }
            }
        }
    }
}

// ---------------- pool + heads ---------------------------------------------

__device__ __forceinline__ int lower_bound_i(const int* __restrict__ a, int n, int v) {
    int lo = 0, hi = n;
    while (lo < hi) {
        int mid = (lo + hi) >> 1;
        if (a[mid] < v) lo = mid + 1; else hi = mid;
    }
    return lo;
}

__global__ __launch_bounds__(128) void pool_kernel(
    const float* __restrict__ h, const int* __restrict__ batch,
    float* __restrict__ pooled, int n_nodes, int n_graphs)
{
    int g = blockIdx.x;
    int lo = lower_bound_i(batch, n_nodes, g);
    int hi = lower_bound_i(batch, n_nodes, g + 1);
    int j = threadIdx.x;
    float acc = 0.f;
    for (int i = lo; i < hi; ++i)
        acc += h[(size_t)i * IN_DIM + j];
    float cnt = (float)(hi - lo);
    pooled[(size_t)g * IN_DIM + j] = acc / fmaxf(cnt, 1.0f);
}

__global__ __launch_bounds__(64) void head_kernel(
    const float* __restrict__ pooled,
    const float* __restrict__ Ws,  const float* __restrict__ bs,
    const float* __restrict__ WlS, const float* __restrict__ blS,
    const float* __restrict__ WlP, const float* __restrict__ blP,
    const float* __restrict__ WnR, const float* __restrict__ bnR,
    float* __restrict__ out, int n_graphs)
{
    int g = blockIdx.x;
    int j = threadIdx.x;
    const float* p = pooled + (size_t)g * IN_DIM;
    float acc = bs[j];
#pragma unroll 8
    for (int k = 0; k < IN_DIM; ++k)
        acc = fmaf(p[k], Ws[k * 64 + j], acc);
    float gj = fmaxf(acc, 0.f);
    float s1 = gj * WlS[j];
    float s2 = gj * WlP[j];
    float s3 = gj * WnR[j];
#pragma unroll
    for (int off = 32; off > 0; off >>= 1) {
        s1 += __shfl_down(s1, off);
        s2 += __shfl_down(s2, off);
        s3 += __shfl_down(s3, off);
    }
    if (j == 0) {
        out[g]                = s1 + blS[0];
        out[n_graphs + g]     = s2 + blP[0];
        out[2 * n_graphs + g] = s3 + bnR[0];
    }
}

// ---------------- launch ---------------------------------------------------

extern "C" void kernel_launch(void* const* d_in, const int* in_sizes, int n_in,
                              void* d_out, int out_size, void* d_ws, size_t ws_size,
                              hipStream_t stream)
{
    const float* x   = (const float*)d_in[0];
    const int*   ei  = (const int*)d_in[1];
    const int*   bat = (const int*)d_in[2];
    const float* W1a = (const float*)d_in[3];
    const float* b1a = (const float*)d_in[4];
    const float* W1b = (const float*)d_in[5];
    const float* b1b = (const float*)d_in[6];
    const float* W2a = (const float*)d_in[7];
    const float* b2a = (const float*)d_in[8];
    const float* W2b = (const float*)d_in[9];
    const float* b2b = (const float*)d_in[10];
    const float* Ws  = (const float*)d_in[11];
    const float* bs  = (const float*)d_in[12];
    const float* WlS = (const float*)d_in[13];
    const float* blS = (const float*)d_in[14];
    const float* WlP = (const float*)d_in[15];
    const float* blP = (const float*)d_in[16];
    const float* WnR = (const float*)d_in[17];
    const float* bnR = (const float*)d_in[18];

    const int n_nodes  = in_sizes[0] / IN_DIM;
    const int n_edges  = in_sizes[1] / 2;
    const int n_graphs = out_size / 3;
    const int* src = ei;
    const int* dst = ei + n_edges;

    const size_t node_elems   = (size_t)n_nodes * IN_DIM;
    const size_t pooled_elems = (size_t)n_graphs * IN_DIM;

    float* xbf    = (float*)d_ws;               // bf16 mirror slot
    float* buf2   = xbf  + node_elems;
    float* bufA   = buf2 + node_elems;          // gather output; buckets alias
    float* pooled = bufA + node_elems;
    int* row_start = (int*)(pooled + pooled_elems);   // n_nodes + 1
    int* bcur      = row_start + (n_nodes + 1);       // NFINE bucket cursors
    int* csr_src   = bcur + NFINE;                    // n_edges
    unsigned short* wt_h = (unsigned short*)(csr_src + n_edges);  // 4 * 16384
    unsigned short* wt_l = wt_h + 4 * 16384;

    unsigned short* xb = (unsigned short*)xbf;
    const int cap = n_edges / NFINE + 2048;           // ~18 sigma slack
    int2* buckets = (int2*)bufA;                      // 128*cap*8B ~= 15MB

    const int gatherblocks = (int)(((size_t)n_nodes * 16 + 255) / 256);
    const int mlpblocks = (n_nodes + 63) / 64;
    const int binblocks = (n_edges + BIN_EPB - 1) / BIN_EPB;
    const int n8 = (int)(node_elems / 8);
    const int cvtblocks = (n8 + 255) / 256;

    // ---- weight conversion + CSR build ----
    conv_weights_kernel<<<256, 256, 0, stream>>>(W1a, W1b, W2a, W2b, wt_h, wt_l);
    hipMemsetAsync(bcur, 0, NFINE * sizeof(int), stream);
    bin_kernel<<<binblocks, 256, 0, stream>>>(src, dst, buckets, bcur,
                                              n_edges, n_nodes, cap);
    csr_fused_kernel<<<NFINE, 512, 0, stream>>>(buckets, bcur, row_start,
                                                csr_src, cap, n_nodes, n_edges);

    // ---- layer 1 ----
    f32_to_bf16_kernel<<<cvtblocks, 256, 0, stream>>>((const float4*)x, (uint4*)xb, n8);
    gather_agg_bf16_kernel<<<gatherblocks, 256, 0, stream>>>(
        x, (const uint4*)xb, row_start, csr_src, bufA, n_nodes);
    fused_mlp_kernel<true><<<mlpblocks, 256, 0, stream>>>(
        bufA, wt_h, wt_l, b1a, wt_h + 16384, wt_l + 16384, b1b,
        buf2, xb, n_nodes);

    // ---- layer 2 ----
    gather_agg_bf16_kernel<<<gatherblocks, 256, 0, stream>>>(
        buf2, (const uint4*)xb, row_start, csr_src, bufA, n_nodes);
    fused_mlp_kernel<false><<<mlpblocks, 256, 0, stream>>>(
        bufA, wt_h + 2 * 16384, wt_l + 2 * 16384, b2a,
        wt_h + 3 * 16384, wt_l + 3 * 16384, b2b,
        buf2, nullptr, n_nodes);

    // ---- pool + heads ----
    pool_kernel<<<n_graphs, 128, 0, stream>>>(buf2, bat, pooled, n_nodes, n_graphs);
    head_kernel<<<n_graphs, 64, 0, stream>>>(pooled, Ws, bs, WlS, blS, WlP, blP,
                                             WnR, bnR, (float*)d_out, n_graphs);
}

// Round 17
// 370.068 us; speedup vs baseline: 1.1338x; 1.0044x over previous
//
#include <hip/hip_runtime.h>
#include <hip/hip_bf16.h>

// ---------------------------------------------------------------------------
// GIN multi-task forward on MI355X.
// R17: XCD-aligned gather->MLP data placement. R16 analysis: gather writer
// block for node n is n/16 (XCD (n/16)%8) but MLP reader block is n/64
// (XCD (n/64)%8) -> 7/8 of MLP A-loads are cross-XCD misses (~900cyc),
// explaining the structure-invariant ~50us MLP. Fix: swizzle gather's
// node-group->block mapping so group g runs on XCD (g/4)%8, putting all of
// MLP block j's A rows (groups 4j..4j+3) in XCD j%8's L2. Layer-2 gather's
// self-term reads align the same way. Everything else identical to R16.
// ---------------------------------------------------------------------------

#define IN_DIM 128
#define NFINE 128        // fine dst buckets (16 per XCD)
#define BIN_EPB 4096     // edges per bin block (16/thread)
#define SRCCH 16         // src chunks per dst row (sorted order)
#define NSLOT 6400       // >= 391 * SRCCH
#define SPT 13           // scan slots per thread (512*13 >= 6400)

typedef float  f32x4  __attribute__((ext_vector_type(4)));
typedef short  bf16x4 __attribute__((ext_vector_type(4)));
typedef short  bf16x8 __attribute__((ext_vector_type(8)));

__device__ __forceinline__ unsigned short bf16_rne(float v) {
    unsigned u = __float_as_uint(v);
    unsigned t = u + 0x7fffu + ((u >> 16) & 1u);
    return (unsigned short)(t >> 16);
}

// ---------------- fp32 -> bf16 convert (RNE), 8 elems/thread ---------------

__global__ __launch_bounds__(256) void f32_to_bf16_kernel(
    const float4* __restrict__ in, uint4* __restrict__ out, int n8)
{
    int i = blockIdx.x * 256 + threadIdx.x;
    if (i >= n8) return;
    float4 a = in[i * 2];
    float4 b = in[i * 2 + 1];
    float v[8] = {a.x, a.y, a.z, a.w, b.x, b.y, b.z, b.w};
    unsigned r[4];
#pragma unroll
    for (int j = 0; j < 4; ++j)
        r[j] = (unsigned)bf16_rne(v[j * 2]) | ((unsigned)bf16_rne(v[j * 2 + 1]) << 16);
    out[i] = make_uint4(r[0], r[1], r[2], r[3]);
}

// ---------------- weight convert: W[k][n] fp32 -> Wt_h/Wt_l[n][k] bf16 -----

__global__ __launch_bounds__(256) void conv_weights_kernel(
    const float* __restrict__ W0, const float* __restrict__ W1,
    const float* __restrict__ W2, const float* __restrict__ W3,
    unsigned short* __restrict__ Wh, unsigned short* __restrict__ Wl)
{
    int m   = blockIdx.x >> 6;
    int idx = (blockIdx.x & 63) * 256 + threadIdx.x;
    const float* W = (m == 0) ? W0 : (m == 1) ? W1 : (m == 2) ? W2 : W3;
    int k = idx >> 7, n = idx & 127;
    float v = W[idx];
    unsigned short hh = bf16_rne(v);
    float hf = __uint_as_float(((unsigned)hh) << 16);
    unsigned short ll = bf16_rne(v - hf);
    Wh[m * 16384 + n * 128 + k] = hh;
    Wl[m * 16384 + n * 128 + k] = ll;
}

// ---------------- CSR build: 128-way bin -> fused hist/scan/fill -----------

__global__ __launch_bounds__(256) void bin_kernel(
    const int* __restrict__ src, const int* __restrict__ dst,
    int2* __restrict__ buckets, int* __restrict__ bcur,
    int n_edges, int n_nodes, int cap)
{
    __shared__ int cnt[NFINE];
    __shared__ int base[NFINE];
    for (int i = threadIdx.x; i < NFINE; i += 256) cnt[i] = 0;
    __syncthreads();

    const int e0 = blockIdx.x * BIN_EPB + threadIdx.x * 16;
    int ne = n_edges - e0;
    if (ne < 0) ne = 0;
    if (ne > 16) ne = 16;

    int d[16], s[16], off[16];
    if (ne == 16) {
#pragma unroll
        for (int q = 0; q < 4; ++q) {
            int4 dv = *(const int4*)(dst + e0 + q * 4);
            int4 sv = *(const int4*)(src + e0 + q * 4);
            d[q * 4 + 0] = dv.x; d[q * 4 + 1] = dv.y;
            d[q * 4 + 2] = dv.z; d[q * 4 + 3] = dv.w;
            s[q * 4 + 0] = sv.x; s[q * 4 + 1] = sv.y;
            s[q * 4 + 2] = sv.z; s[q * 4 + 3] = sv.w;
        }
    } else {
#pragma unroll
        for (int j = 0; j < 16; ++j) {
            d[j] = (j < ne) ? dst[e0 + j] : 0;
            s[j] = (j < ne) ? src[e0 + j] : 0;
        }
    }
#pragma unroll
    for (int j = 0; j < 16; ++j)
        if (j < ne) {
            int b = (int)(((long long)d[j] * NFINE) / n_nodes);
            off[j] = atomicAdd(&cnt[b], 1);
        }
    __syncthreads();
    for (int i = threadIdx.x; i < NFINE; i += 256)
        base[i] = atomicAdd(&bcur[i], cnt[i]);
    __syncthreads();
#pragma unroll
    for (int j = 0; j < 16; ++j)
        if (j < ne) {
            int b = (int)(((long long)d[j] * NFINE) / n_nodes);
            buckets[(size_t)b * cap + base[b] + off[j]] = make_int2(d[j], s[j]);
        }
}

// One block per fine bucket. Per-(node, src-chunk16) LDS histogram, blocked
// exclusive scan (13 slots/thread), row_start write, LDS-cursor fill ->
// csr rows stored sorted by src chunk (gather L2 locality).
__global__ __launch_bounds__(512) void csr_fused_kernel(
    const int2* __restrict__ buckets, const int* __restrict__ bcnt,
    int* __restrict__ row_start, int* __restrict__ csr_src,
    int cap, int n_nodes, int n_edges)
{
    __shared__ int bc[NFINE];
    __shared__ int h[NSLOT];
    __shared__ int tsum[512];
    __shared__ int bbase_s;

    const int b = blockIdx.x;
    const int t = threadIdx.x;
    const int lo_n = (int)(((long long)b * n_nodes + NFINE - 1) / NFINE);
    const int hi_n = (int)(((long long)(b + 1) * n_nodes + NFINE - 1) / NFINE);
    const int sl = hi_n - lo_n;

    if (t < NFINE) bc[t] = bcnt[t];
    for (int i = t; i < NSLOT; i += 512) h[i] = 0;
    __syncthreads();
    if (t == 0) {
        int s = 0;
        for (int i = 0; i < b; ++i) s += bc[i];
        bbase_s = s;
    }
    const int nb = bc[b];
    const int2* bp = buckets + (size_t)b * cap;
    __syncthreads();

    // pass 1: per-(node, src-chunk) histogram
    for (int i = t; i < nb; i += 512) {
        int2 e = bp[i];
        int key = (e.x - lo_n) * SRCCH + (int)(((long long)e.y * SRCCH) / n_nodes);
        atomicAdd(&h[key], 1);
    }
    __syncthreads();

    // blocked exclusive scan over NSLOT entries (SPT per thread)
    int base = 0;
#pragma unroll
    for (int j = 0; j < SPT; ++j) {
        int slot = t * SPT + j;
        if (slot < NSLOT) {
            int v = h[slot];
            h[slot] = base;
            base += v;
        }
    }
    tsum[t] = base;
    __syncthreads();
    for (int off = 1; off < 512; off <<= 1) {
        int tmp = (t >= off) ? tsum[t - off] : 0;
        __syncthreads();
        tsum[t] += tmp;
        __syncthreads();
    }
    int texcl = tsum[t] - base + bbase_s;
#pragma unroll
    for (int j = 0; j < SPT; ++j) {
        int slot = t * SPT + j;
        if (slot < NSLOT) h[slot] += texcl;
    }
    __syncthreads();
    for (int i = t; i < sl; i += 512) row_start[lo_n + i] = h[i * SRCCH];
    if (b == NFINE - 1 && t == 0) row_start[n_nodes] = n_edges;
    __syncthreads();

    // pass 2: fill with LDS cursors (exclusive csr window, full-line writes)
    for (int i = t; i < nb; i += 512) {
        int2 e = bp[i];
        int key = (e.x - lo_n) * SRCCH + (int)(((long long)e.y * SRCCH) / n_nodes);
        csr_src[atomicAdd(&h[key], 1)] = e.y;
    }
}

// ---------------- gather aggregation (bf16 neighbors, fp32 self/acc) -------
// R17: block->node-group swizzle. Group g (16 nodes) runs on a block with
// blockIdx%8 == (g/4)%8, so the 64-node MLP tile j (groups 4j..4j+3) finds
// all its A rows in XCD (j%8)'s L2.

__device__ __forceinline__ void add_row8(float acc[8], uint4 r) {
    union { unsigned u; float f; } c;
    c.u = r.x << 16;         acc[0] += c.f;
    c.u = r.x & 0xffff0000u; acc[1] += c.f;
    c.u = r.y << 16;         acc[2] += c.f;
    c.u = r.y & 0xffff0000u; acc[3] += c.f;
    c.u = r.z << 16;         acc[4] += c.f;
    c.u = r.z & 0xffff0000u; acc[5] += c.f;
    c.u = r.w << 16;         acc[6] += c.f;
    c.u = r.w & 0xffff0000u; acc[7] += c.f;
}

__global__ __launch_bounds__(256) void gather_agg_bf16_kernel(
    const float* __restrict__ xf,    // fp32 rows (self term)
    const uint4* __restrict__ xb,    // bf16 rows, 16 uint4/row
    const int* __restrict__ row_start, const int* __restrict__ csr_src,
    float* __restrict__ out, int n_nodes)
{
    // swizzle block -> 16-node group so group g lands on XCD (g/4)%8
    int blk = blockIdx.x;
    int nfull = (gridDim.x >> 5) << 5;   // multiple of 32
    int group;
    if (blk < nfull) {
        int x = blk & 7;
        int q = blk >> 3;
        group = ((q >> 2) << 5) + (x << 2) + (q & 3);
    } else {
        group = blk;                     // tail unswizzled
    }

    int node = group * 16 + (threadIdx.x >> 4);
    int lane = threadIdx.x & 15;
    if (node >= n_nodes) return;
    int lo = row_start[node];
    int hi = row_start[node + 1];

    const f32x4* xfr = (const f32x4*)(xf + (size_t)node * IN_DIM + lane * 8);
    f32x4 a0 = xfr[0];
    f32x4 a1 = xfr[1];
    float acc[8] = {a0.x, a0.y, a0.z, a0.w, a1.x, a1.y, a1.z, a1.w};

    int e = lo;
    for (; e + 3 < hi; e += 4) {
        int s0 = csr_src[e];
        int s1 = csr_src[e + 1];
        int s2 = csr_src[e + 2];
        int s3 = csr_src[e + 3];
        uint4 r0 = xb[(size_t)s0 * 16 + lane];
        uint4 r1 = xb[(size_t)s1 * 16 + lane];
        uint4 r2 = xb[(size_t)s2 * 16 + lane];
        uint4 r3 = xb[(size_t)s3 * 16 + lane];
        add_row8(acc, r0);
        add_row8(acc, r1);
        add_row8(acc, r2);
        add_row8(acc, r3);
    }
    for (; e < hi; ++e) {
        uint4 r = xb[(size_t)csr_src[e] * 16 + lane];
        add_row8(acc, r);
    }

    // normal stores: bufA stays in THIS XCD's L2 for the aligned MLP reader
    f32x4* op = (f32x4*)(out + (size_t)node * IN_DIM + lane * 8);
    op[0] = (f32x4){acc[0], acc[1], acc[2], acc[3]};
    op[1] = (f32x4){acc[4], acc[5], acc[6], acc[7]};
}

// ---------------- fused MLP: relu(relu(A@Wa+ba)@Wb+bb) ---------------------
// Block = 256 thr (4 waves), 64 rows x 128 cols. Each wave owns a 32-row x
// 64-col quadrant: 2 row-tiles x 4 col-tiles = 8 indep acc chains, W shared
// across row-tiles (6 MFMAs per 2 W loads). (R13/R16 structure.)
#define HSTRIDE 132

template <bool EMIT_BF16>
__global__ __launch_bounds__(256) void fused_mlp_kernel(
    const float* __restrict__ A,
    const unsigned short* __restrict__ Wa_h, const unsigned short* __restrict__ Wa_l,
    const float* __restrict__ ba,
    const unsigned short* __restrict__ Wb_h, const unsigned short* __restrict__ Wb_l,
    const float* __restrict__ bb,
    float* __restrict__ C, unsigned short* __restrict__ Cb, int M)
{
    __shared__ __align__(16) unsigned short Hh[64][HSTRIDE];
    __shared__ __align__(16) unsigned short Hl[64][HSTRIDE];

    const int t    = threadIdx.x;
    const int wave = t >> 6;
    const int lane = t & 63;
    const int l15  = lane & 15;
    const int quad = lane >> 4;
    const int rw   = (wave & 1) * 32;        // row quadrant base within block
    const int cw   = (wave >> 1) * 64;       // col quadrant base
    const int row0 = blockIdx.x * 64 + rw;

    f32x4 acc[2][4];
#pragma unroll
    for (int ti = 0; ti < 2; ++ti)
#pragma unroll
        for (int ct = 0; ct < 4; ++ct) acc[ti][ct] = {0.f, 0.f, 0.f, 0.f};

    // ---- stage 1: A (global fp32, split bf16) @ Wa ----
    {
        int ar0 = row0 + l15;
        int ar1 = row0 + 16 + l15;
        const float* ap0 = A + (size_t)((ar0 < M) ? ar0 : (M - 1)) * IN_DIM + quad * 8;
        const float* ap1 = A + (size_t)((ar1 < M) ? ar1 : (M - 1)) * IN_DIM + quad * 8;
#pragma unroll
        for (int k0 = 0; k0 < IN_DIM; k0 += 32) {
            bf16x8 ah[2], al[2];
#pragma unroll
            for (int ti = 0; ti < 2; ++ti) {
                const float* ap = ti ? ap1 : ap0;
                f32x4 v0 = *(const f32x4*)(ap + k0);
                f32x4 v1 = *(const f32x4*)(ap + k0 + 4);
                float v[8] = {v0.x, v0.y, v0.z, v0.w, v1.x, v1.y, v1.z, v1.w};
                unsigned short h[8], l[8];
#pragma unroll
                for (int j = 0; j < 8; ++j) {
                    unsigned short hh = bf16_rne(v[j]);
                    h[j] = hh;
                    l[j] = bf16_rne(v[j] - __uint_as_float(((unsigned)hh) << 16));
                }
                ah[ti] = *(const bf16x8*)h;
                al[ti] = *(const bf16x8*)l;
            }
#pragma unroll
            for (int ct = 0; ct < 4; ++ct) {
                const size_t woff = (size_t)(cw + ct * 16 + l15) * IN_DIM + k0 + quad * 8;
                bf16x8 wh = *(const bf16x8*)(Wa_h + woff);
                bf16x8 wl = *(const bf16x8*)(Wa_l + woff);
                acc[0][ct] = __builtin_amdgcn_mfma_f32_16x16x32_bf16(ah[0], wh, acc[0][ct], 0, 0, 0);
                acc[1][ct] = __builtin_amdgcn_mfma_f32_16x16x32_bf16(ah[1], wh, acc[1][ct], 0, 0, 0);
                acc[0][ct] = __builtin_amdgcn_mfma_f32_16x16x32_bf16(al[0], wh, acc[0][ct], 0, 0, 0);
                acc[1][ct] = __builtin_amdgcn_mfma_f32_16x16x32_bf16(al[1], wh, acc[1][ct], 0, 0, 0);
                acc[0][ct] = __builtin_amdgcn_mfma_f32_16x16x32_bf16(ah[0], wl, acc[0][ct], 0, 0, 0);
                acc[1][ct] = __builtin_amdgcn_mfma_f32_16x16x32_bf16(ah[1], wl, acc[1][ct], 0, 0, 0);
            }
        }
    }

    // ---- epilogue 1: h = relu(acc + ba) -> LDS quadrant (split bf16) ----
#pragma unroll
    for (int ti = 0; ti < 2; ++ti) {
#pragma unroll
        for (int ct = 0; ct < 4; ++ct) {
            int col = cw + ct * 16 + l15;
            float b = ba[col];
#pragma unroll
            for (int r = 0; r < 4; ++r) {
                int rl = rw + ti * 16 + quad * 4 + r;
                float v = fmaxf(acc[ti][ct][r] + b, 0.f);
                unsigned short hh = bf16_rne(v);
                Hh[rl][col] = hh;
                Hl[rl][col] = bf16_rne(v - __uint_as_float(((unsigned)hh) << 16));
            }
            acc[ti][ct] = {0.f, 0.f, 0.f, 0.f};
        }
    }
    __syncthreads();

    // ---- stage 2: h (LDS, split bf16) @ Wb ----
#pragma unroll
    for (int k0 = 0; k0 < IN_DIM; k0 += 32) {
        const int hk = k0 + quad * 8;
        bf16x8 ah[2], al[2];
#pragma unroll
        for (int ti = 0; ti < 2; ++ti) {
            const int hr = rw + ti * 16 + l15;
            bf16x4 h0 = *(const bf16x4*)&Hh[hr][hk];
            bf16x4 h1 = *(const bf16x4*)&Hh[hr][hk + 4];
            bf16x4 l0 = *(const bf16x4*)&Hl[hr][hk];
            bf16x4 l1 = *(const bf16x4*)&Hl[hr][hk + 4];
            ah[ti] = __builtin_shufflevector(h0, h1, 0, 1, 2, 3, 4, 5, 6, 7);
            al[ti] = __builtin_shufflevector(l0, l1, 0, 1, 2, 3, 4, 5, 6, 7);
        }
#pragma unroll
        for (int ct = 0; ct < 4; ++ct) {
            const size_t woff = (size_t)(cw + ct * 16 + l15) * IN_DIM + k0 + quad * 8;
            bf16x8 wh = *(const bf16x8*)(Wb_h + woff);
            bf16x8 wl = *(const bf16x8*)(Wb_l + woff);
            acc[0][ct] = __builtin_amdgcn_mfma_f32_16x16x32_bf16(ah[0], wh, acc[0][ct], 0, 0, 0);
            acc[1][ct] = __builtin_amdgcn_mfma_f32_16x16x32_bf16(ah[1], wh, acc[1][ct], 0, 0, 0);
            acc[0][ct] = __builtin_amdgcn_mfma_f32_16x16x32_bf16(al[0], wh, acc[0][ct], 0, 0, 0);
            acc[1][ct] = __builtin_amdgcn_mfma_f32_16x16x32_bf16(al[1], wh, acc[1][ct], 0, 0, 0);
            acc[0][ct] = __builtin_amdgcn_mfma_f32_16x16x32_bf16(ah[0], wl, acc[0][ct], 0, 0, 0);
            acc[1][ct] = __builtin_amdgcn_mfma_f32_16x16x32_bf16(ah[1], wl, acc[1][ct], 0, 0, 0);
        }
    }

    // ---- epilogue 2: out = relu(acc + bb) -> C (+ bf16 mirror) ----
#pragma unroll
    for (int ti = 0; ti < 2; ++ti) {
        const int rbase = row0 + ti * 16 + quad * 4;
#pragma unroll
        for (int ct = 0; ct < 4; ++ct) {
            int col = cw + ct * 16 + l15;
            float b = bb[col];
#pragma unroll
            for (int r = 0; r < 4; ++r) {
                int row = rbase + r;
                if (row < M) {
                    float o = fmaxf(acc[ti][ct][r] + b, 0.f);
                    C[(size_t)row * IN_DIM + col] = o;
                    if (EMIT_BF16)
                        Cb[(size_t)row * IN_DIM + col] = bf16_rne(o);
                }
            }
        }
    }
}

// ---------------- pool + heads ---------------------------------------------

__device__ __forceinline__ int lower_bound_i(const int* __restrict__ a, int n, int v) {
    int lo = 0, hi = n;
    while (lo < hi) {
        int mid = (lo + hi) >> 1;
        if (a[mid] < v) lo = mid + 1; else hi = mid;
    }
    return lo;
}

__global__ __launch_bounds__(128) void pool_kernel(
    const float* __restrict__ h, const int* __restrict__ batch,
    float* __restrict__ pooled, int n_nodes, int n_graphs)
{
    int g = blockIdx.x;
    int lo = lower_bound_i(batch, n_nodes, g);
    int hi = lower_bound_i(batch, n_nodes, g + 1);
    int j = threadIdx.x;
    float acc = 0.f;
    for (int i = lo; i < hi; ++i)
        acc += h[(size_t)i * IN_DIM + j];
    float cnt = (float)(hi - lo);
    pooled[(size_t)g * IN_DIM + j] = acc / fmaxf(cnt, 1.0f);
}

__global__ __launch_bounds__(64) void head_kernel(
    const float* __restrict__ pooled,
    const float* __restrict__ Ws,  const float* __restrict__ bs,
    const float* __restrict__ WlS, const float* __restrict__ blS,
    const float* __restrict__ WlP, const float* __restrict__ blP,
    const float* __restrict__ WnR, const float* __restrict__ bnR,
    float* __restrict__ out, int n_graphs)
{
    int g = blockIdx.x;
    int j = threadIdx.x;
    const float* p = pooled + (size_t)g * IN_DIM;
    float acc = bs[j];
#pragma unroll 8
    for (int k = 0; k < IN_DIM; ++k)
        acc = fmaf(p[k], Ws[k * 64 + j], acc);
    float gj = fmaxf(acc, 0.f);
    float s1 = gj * WlS[j];
    float s2 = gj * WlP[j];
    float s3 = gj * WnR[j];
#pragma unroll
    for (int off = 32; off > 0; off >>= 1) {
        s1 += __shfl_down(s1, off);
        s2 += __shfl_down(s2, off);
        s3 += __shfl_down(s3, off);
    }
    if (j == 0) {
        out[g]                = s1 + blS[0];
        out[n_graphs + g]     = s2 + blP[0];
        out[2 * n_graphs + g] = s3 + bnR[0];
    }
}

// ---------------- launch ---------------------------------------------------

extern "C" void kernel_launch(void* const* d_in, const int* in_sizes, int n_in,
                              void* d_out, int out_size, void* d_ws, size_t ws_size,
                              hipStream_t stream)
{
    const float* x   = (const float*)d_in[0];
    const int*   ei  = (const int*)d_in[1];
    const int*   bat = (const int*)d_in[2];
    const float* W1a = (const float*)d_in[3];
    const float* b1a = (const float*)d_in[4];
    const float* W1b = (const float*)d_in[5];
    const float* b1b = (const float*)d_in[6];
    const float* W2a = (const float*)d_in[7];
    const float* b2a = (const float*)d_in[8];
    const float* W2b = (const float*)d_in[9];
    const float* b2b = (const float*)d_in[10];
    const float* Ws  = (const float*)d_in[11];
    const float* bs  = (const float*)d_in[12];
    const float* WlS = (const float*)d_in[13];
    const float* blS = (const float*)d_in[14];
    const float* WlP = (const float*)d_in[15];
    const float* blP = (const float*)d_in[16];
    const float* WnR = (const float*)d_in[17];
    const float* bnR = (const float*)d_in[18];

    const int n_nodes  = in_sizes[0] / IN_DIM;
    const int n_edges  = in_sizes[1] / 2;
    const int n_graphs = out_size / 3;
    const int* src = ei;
    const int* dst = ei + n_edges;

    const size_t node_elems   = (size_t)n_nodes * IN_DIM;
    const size_t pooled_elems = (size_t)n_graphs * IN_DIM;

    float* xbf    = (float*)d_ws;               // bf16 mirror slot
    float* buf2   = xbf  + node_elems;
    float* bufA   = buf2 + node_elems;          // gather output; buckets alias
    float* pooled = bufA + node_elems;
    int* row_start = (int*)(pooled + pooled_elems);   // n_nodes + 1
    int* bcur      = row_start + (n_nodes + 1);       // NFINE bucket cursors
    int* csr_src   = bcur + NFINE;                    // n_edges
    unsigned short* wt_h = (unsigned short*)(csr_src + n_edges);  // 4 * 16384
    unsigned short* wt_l = wt_h + 4 * 16384;

    unsigned short* xb = (unsigned short*)xbf;
    const int cap = n_edges / NFINE + 2048;           // ~18 sigma slack
    int2* buckets = (int2*)bufA;                      // 128*cap*8B ~= 15MB

    const int gatherblocks = (int)(((size_t)n_nodes * 16 + 255) / 256);
    const int mlpblocks = (n_nodes + 63) / 64;
    const int binblocks = (n_edges + BIN_EPB - 1) / BIN_EPB;
    const int n8 = (int)(node_elems / 8);
    const int cvtblocks = (n8 + 255) / 256;

    // ---- weight conversion + CSR build ----
    conv_weights_kernel<<<256, 256, 0, stream>>>(W1a, W1b, W2a, W2b, wt_h, wt_l);
    hipMemsetAsync(bcur, 0, NFINE * sizeof(int), stream);
    bin_kernel<<<binblocks, 256, 0, stream>>>(src, dst, buckets, bcur,
                                              n_edges, n_nodes, cap);
    csr_fused_kernel<<<NFINE, 512, 0, stream>>>(buckets, bcur, row_start,
                                                csr_src, cap, n_nodes, n_edges);

    // ---- layer 1 ----
    f32_to_bf16_kernel<<<cvtblocks, 256, 0, stream>>>((const float4*)x, (uint4*)xb, n8);
    gather_agg_bf16_kernel<<<gatherblocks, 256, 0, stream>>>(
        x, (const uint4*)xb, row_start, csr_src, bufA, n_nodes);
    fused_mlp_kernel<true><<<mlpblocks, 256, 0, stream>>>(
        bufA, wt_h, wt_l, b1a, wt_h + 16384, wt_l + 16384, b1b,
        buf2, xb, n_nodes);

    // ---- layer 2 ----
    gather_agg_bf16_kernel<<<gatherblocks, 256, 0, stream>>>(
        buf2, (const uint4*)xb, row_start, csr_src, bufA, n_nodes);
    fused_mlp_kernel<false><<<mlpblocks, 256, 0, stream>>>(
        bufA, wt_h + 2 * 16384, wt_l + 2 * 16384, b2a,
        wt_h + 3 * 16384, wt_l + 3 * 16384, b2b,
        buf2, nullptr, n_nodes);

    // ---- pool + heads ----
    pool_kernel<<<n_graphs, 128, 0, stream>>>(buf2, bat, pooled, n_nodes, n_graphs);
    head_kernel<<<n_graphs, 64, 0, stream>>>(pooled, Ws, bs, WlS, blS, WlP, blP,
                                             WnR, bnR, (float*)d_out, n_graphs);
}